// Round 7
// baseline (331.810 us; speedup 1.0000x reference)
//
#include <hip/hip_runtime.h>
#include <stdint.h>

typedef unsigned short u16;
typedef unsigned int u32;

typedef __bf16 bf8 __attribute__((ext_vector_type(8)));
typedef bf8 bf8a __attribute__((may_alias));
typedef float f32x4 __attribute__((ext_vector_type(4)));
typedef uint2 uint2a __attribute__((may_alias));
typedef ushort4 ushort4a __attribute__((may_alias));
typedef float4 float4a __attribute__((may_alias));

#define MFMA_BF16(a, b, c) __builtin_amdgcn_mfma_f32_16x16x32_bf16((a), (b), (c), 0, 0, 0)

__device__ __forceinline__ u16 f2b(float x) {
  u32 u = __float_as_uint(x);
  return (u16)((u + 0x7fffu + ((u >> 16) & 1u)) >> 16);  // RNE
}
__device__ __forceinline__ void async16(const u16* g, void* l) {
  __builtin_amdgcn_global_load_lds((const __attribute__((address_space(1))) u32*)g,
                                   (__attribute__((address_space(3))) u32*)l, 16, 0, 0);
}

// ---------------------------------------------------------------------------
// prep_inputs: fused {src fp32->bf16 convert (blocks 0..4095)} +
//              {4x weight transpose+convert (blocks 4096..5119)}
// ---------------------------------------------------------------------------
__global__ __launch_bounds__(256) void prep_inputs(
    const float* __restrict__ src, u16* __restrict__ dst,
    const float* __restrict__ w0, const float* __restrict__ w1,
    const float* __restrict__ w2, const float* __restrict__ w3,
    u16* __restrict__ t0, u16* __restrict__ t1, u16* __restrict__ t2, u16* __restrict__ t3) {
  const int bid = blockIdx.x, tid = threadIdx.x;
  if (bid < 4096) {  // convert_src
    const int i = bid * 256 + tid;
    float4 v = *(const float4a*)(src + i * 4);
    ushort4 o;
    o.x = f2b(v.x); o.y = f2b(v.y); o.z = f2b(v.z); o.w = f2b(v.w);
    *(ushort4a*)(dst + i * 4) = o;
    return;
  }
  // transpose4 (whole block takes this path -> barrier is uniform)
  const int b2 = bid - 4096;
  const int z = b2 >> 8, xy = b2 & 255;
  const int bx = xy & 15, by = xy >> 4;
  const float* W = z == 0 ? w0 : z == 1 ? w1 : z == 2 ? w2 : w3;
  u16* T = z == 0 ? t0 : z == 1 ? t1 : z == 2 ? t2 : t3;
  __shared__ __align__(8) u16 tile[64][68];
  const int ty = tid >> 4, tx = tid & 15;
  const int kb = by * 64, nb = bx * 64;
#pragma unroll
  for (int i = 0; i < 4; ++i) {
    int lk = ty + i * 16;
    float4 v = *(const float4a*)(W + (kb + lk) * 1024 + nb + tx * 4);
    ushort4 h;
    h.x = f2b(v.x); h.y = f2b(v.y); h.z = f2b(v.z); h.w = f2b(v.w);
    *(ushort4a*)&tile[lk][tx * 4] = h;
  }
  __syncthreads();
#pragma unroll
  for (int i = 0; i < 4; ++i) {
    int ln = ty + i * 16;
    ushort4 v;
    v.x = tile[tx * 4 + 0][ln];
    v.y = tile[tx * 4 + 1][ln];
    v.z = tile[tx * 4 + 2][ln];
    v.w = tile[tx * 4 + 3][ln];
    *(ushort4a*)(T + (nb + ln) * 1024 + kb + tx * 4) = v;
  }
}

// ---------------------------------------------------------------------------
// EB precompute: fp32 [2048][2048] -> bf16 sign(b)*exp(b), 16x16-tiled layout.
// (Runs after QKV GEMM; output aliases the then-dead srcB region.)
// ---------------------------------------------------------------------------
__global__ __launch_bounds__(256) void prep_eb(const float* __restrict__ EB,
                                               u16* __restrict__ E2) {
  const int gid = blockIdx.x * 256 + threadIdx.x;
  const int s = gid >> 9;            // 512 float4 per row
  const int t = (gid & 511) * 4;
  const float4 v = *(const float4a*)(EB + s * 2048 + t);
  const float c2 = 1.44269504088896340736f;  // log2(e)
  ushort4 o;
  o.x = f2b(__builtin_amdgcn_exp2f(v.x * c2)) | (u16)((__float_as_uint(v.x) >> 16) & 0x8000u);
  o.y = f2b(__builtin_amdgcn_exp2f(v.y * c2)) | (u16)((__float_as_uint(v.y) >> 16) & 0x8000u);
  o.z = f2b(__builtin_amdgcn_exp2f(v.z * c2)) | (u16)((__float_as_uint(v.z) >> 16) & 0x8000u);
  o.w = f2b(__builtin_amdgcn_exp2f(v.w * c2)) | (u16)((__float_as_uint(v.w) >> 16) & 0x8000u);
  const int ti = ((s >> 4) * 128 + (t >> 4)) * 256 + (s & 15) * 16 + (t & 15);
  *(ushort4a*)(E2 + ti) = o;
}

// ---------------------------------------------------------------------------
// GEMM: C[M][N] = (A[M,1024] * Bt[N,1024]^T + bias[n]) * scale   (m97 structure)
// scale: folds the attention logit scale c1 into Q (z==0) so attn's softmax
// is exp2(sacc) with no per-element multiply.
// ---------------------------------------------------------------------------
__global__ __launch_bounds__(256) void gemm_bt(
    const u16* __restrict__ A,
    const u16* __restrict__ B0, const u16* __restrict__ B1, const u16* __restrict__ B2,
    const float* __restrict__ c0, const float* __restrict__ c1, const float* __restrict__ c2,
    float sc0, float sc1, float sc2,
    u16* __restrict__ O0, u16* __restrict__ O1, u16* __restrict__ O2,
    float* __restrict__ Of, int plain) {
  __shared__ __align__(16) u16 sm[8192];
  u16* As = sm;
  u16* Bs = sm + 4096;
  const int tid = threadIdx.x, lane = tid & 63, w = tid >> 6;
  const int wm = w >> 1, wn = w & 1, quad = lane >> 4, l16 = lane & 15;
  const int z = blockIdx.z;
  const u16* Bt = z == 0 ? B0 : (z == 1 ? B1 : B2);
  const float* bi = z == 0 ? c0 : (z == 1 ? c1 : c2);
  const float sc = z == 0 ? sc0 : (z == 1 ? sc1 : sc2);
  u16* O = z == 0 ? O0 : (z == 1 ? O1 : O2);
  const int row0 = blockIdx.y * 128, col0 = blockIdx.x * 128;

  f32x4 acc[4][4];
#pragma unroll
  for (int i = 0; i < 4; ++i)
#pragma unroll
    for (int j = 0; j < 4; ++j) acc[i][j] = f32x4{0.f, 0.f, 0.f, 0.f};

  const int e0 = tid, e1 = tid + 256;
  const int r0 = e0 >> 2, cc0 = (e0 & 3) * 8;
  const int r1 = e1 >> 2, cc1 = (e1 & 3) * 8;
  const u32 lb0 = (u32)(w * 64) * 16;
  const u32 lb1 = (u32)(w * 64 + 256) * 16;

  for (int k0 = 0; k0 < 1024; k0 += 32) {
    __syncthreads();
    async16(A + (row0 + r0) * 1024 + k0 + cc0, (char*)As + lb0);
    async16(A + (row0 + r1) * 1024 + k0 + cc1, (char*)As + lb1);
    async16(Bt + (col0 + r0) * 1024 + k0 + cc0, (char*)Bs + lb0);
    async16(Bt + (col0 + r1) * 1024 + k0 + cc1, (char*)Bs + lb1);
    __syncthreads();
    bf8a af[4], bfr[4];
#pragma unroll
    for (int i = 0; i < 4; ++i) {
      af[i] = *(const bf8a*)(As + (wm * 64 + i * 16 + l16) * 32 + quad * 8);
      bfr[i] = *(const bf8a*)(Bs + (wn * 64 + i * 16 + l16) * 32 + quad * 8);
    }
#pragma unroll
    for (int mt = 0; mt < 4; ++mt)
#pragma unroll
      for (int nt = 0; nt < 4; ++nt) acc[mt][nt] = MFMA_BF16(af[mt], bfr[nt], acc[mt][nt]);
  }

#pragma unroll
  for (int nt = 0; nt < 4; ++nt) {
    const int col = col0 + wn * 64 + nt * 16 + l16;
    const float bcol = bi[col];
#pragma unroll
    for (int mt = 0; mt < 4; ++mt) {
#pragma unroll
      for (int r = 0; r < 4; ++r) {
        const int rm = row0 + wm * 64 + mt * 16 + quad * 4 + r;
        const float fv = (acc[mt][nt][r] + bcol) * sc;
        if (plain) {
          Of[rm * 1024 + col] = fv;
        } else {
          const u16 hv = f2b(fv);
          const int s = rm >> 1, b_ = rm & 1, hh = col >> 6, e = col & 63;
          const int p = b_ * 16 + hh;
          if (z < 2) O[(p * 2048 + s) * 64 + e] = hv;  // [pair][s][64]
          else O[(p * 64 + e) * 2048 + s] = hv;        // [pair][e][s] (V^T)
        }
      }
    }
  }
}

// ---------------------------------------------------------------------------
// Flash attention v15 = v13 chassis (QBLK=64, K via global_load_lds dbuf --
// the only K path that pipelines; reg-prefetch of K collapsed in v9/v10/v14)
// + register diet targeting 3 waves/SIMD (combined VGPR+AGPR <= 170):
//   - EB single-buffered, JIT at COMPUTE top (was dbuf: -16 VGPR)
//   - V JIT at PV start (-16 live during the S/softmax pressure peak)
//   - sacc per-tt (-16), softmax interleaved per tt (sm-split style)
//   - c1 folded into Q GEMM (exp2f(sacc) direct: -32 mul/iter/wave)
//   - native __bf16 casts for P pack (compiler cvt; fewer bit-ops)
//   - __launch_bounds__(256,3)
// LDS 50.3KB -> 3 blocks/CU; grid 1024 = 8 xcd * 4 pair * 32 qt (pinned).
// ---------------------------------------------------------------------------
#define STAGE_K(Ksbuf, kt_)                                                         \
  {                                                                                 \
    _Pragma("unroll") for (int c = 0; c < 4; ++c) {                                 \
      const int row_ = c * 32 + w * 8 + r8;                                         \
      async16(Kp + ((kt_) * 128 + row_) * 64 + c16s * 8,                            \
              (char*)(Ksbuf) + (c * 4 + w) * 1024);                                 \
    }                                                                               \
  }

#define COMPUTE(Ksbuf, kt_)                                                         \
  {                                                                                 \
    const int tb16_ = (kt_) * 8 + w * 2;                                            \
    uint2 ebt[2][4]; /* [tt][st] JIT, L2-resident stripe */                         \
    _Pragma("unroll") for (int tt = 0; tt < 2; ++tt)                                \
      _Pragma("unroll") for (int st = 0; st < 4; ++st)                              \
        ebt[tt][st] = *(const uint2a*)(EBp + ((qt * 4 + st) * 128 + tb16_ + tt) * 256 \
                                       + l16 * 16 + quad * 4);                      \
    _Pragma("unroll") for (int tt = 0; tt < 2; ++tt) {                              \
      bf8a kfa[2];                                                                  \
      {                                                                             \
        const int row_ = w * 32 + tt * 16 + l16; /* row_&7 == l16&7 */              \
        _Pragma("unroll") for (int ks = 0; ks < 2; ++ks) {                          \
          const int cc_ = ((ks * 4 + quad) ^ (l16 & 7)) * 8;                        \
          kfa[ks] = *(const bf8a*)((Ksbuf) + row_ * 64 + cc_);                      \
        }                                                                           \
      }                                                                             \
      f32x4 sacc[4];                                                                \
      __builtin_amdgcn_s_setprio(1);                                                \
      _Pragma("unroll") for (int st = 0; st < 4; ++st) {                            \
        f32x4 t0_ = f32x4{0.f, 0.f, 0.f, 0.f};                                      \
        t0_ = MFMA_BF16(kfa[0], qf[st][0], t0_);                                    \
        sacc[st] = MFMA_BF16(kfa[1], qf[st][1], t0_);                               \
      }                                                                             \
      __builtin_amdgcn_s_setprio(0);                                                \
      _Pragma("unroll") for (int st = 0; st < 4; ++st) {                            \
        const uint2 e_ = ebt[tt][st];                                               \
        const float g0 = __uint_as_float(e_.x << 16);                               \
        const float g1 = __uint_as_float(e_.x & 0xffff0000u);                       \
        const float g2 = __uint_as_float(e_.y << 16);                               \
        const float g3 = __uint_as_float(e_.y & 0xffff0000u);                       \
        const float p0 = __builtin_amdgcn_exp2f(sacc[st][0]) * g0;                  \
        const float p1 = __builtin_amdgcn_exp2f(sacc[st][1]) * g1;                  \
        const float p2 = __builtin_amdgcn_exp2f(sacc[st][2]) * g2;                  \
        const float p3 = __builtin_amdgcn_exp2f(sacc[st][3]) * g3;                  \
        lsum[st] += (__builtin_fabsf(p0) + __builtin_fabsf(p1)) +                   \
                    (__builtin_fabsf(p2) + __builtin_fabsf(p3));                    \
        const u16 h0 = __builtin_bit_cast(u16, (__bf16)p0);                         \
        const u16 h1 = __builtin_bit_cast(u16, (__bf16)p1);                         \
        const u16 h2 = __builtin_bit_cast(u16, (__bf16)p2);                         \
        const u16 h3 = __builtin_bit_cast(u16, (__bf16)p3);                         \
        uint2 v_;                                                                   \
        v_.x = (u32)h0 | ((u32)h1 << 16);                                           \
        v_.y = (u32)h2 | ((u32)h3 << 16);                                           \
        *(uint2a*)(Pw + st * 1152 + l16 * 72 + tt * 32 + quad * 8) = v_;            \
      }                                                                             \
    }                                                                               \
    const int tb_ = (kt_) * 128 + w * 32;                                           \
    bf8a vf[4]; /* V^T JIT: L2-resident; pf ds_read partially covers */             \
    _Pragma("unroll") for (int nt = 0; nt < 4; ++nt)                                \
      vf[nt] = *(const bf8a*)(Vp + (nt * 16 + l16) * 2048 + tb_ + quad * 8);        \
    _Pragma("unroll") for (int st = 0; st < 4; ++st) {                              \
      bf8a pf = *(const bf8a*)(Pw + st * 1152 + l16 * 72 + quad * 16);              \
      __builtin_amdgcn_s_setprio(1);                                                \
      _Pragma("unroll") for (int nt = 0; nt < 4; ++nt)                              \
        oacc[st][nt] = MFMA_BF16(vf[nt], pf, oacc[st][nt]);                         \
      __builtin_amdgcn_s_setprio(0);                                                \
    }                                                                               \
  }

__global__ __launch_bounds__(256, 3) void attn_fused(
    const u16* __restrict__ Qw, const u16* __restrict__ Kw, const u16* __restrict__ Vw,
    const u16* __restrict__ EBp, u16* __restrict__ Ao) {
  // LDS map: [0,16384) Ks0, [16384,32768) Ks1 (K tile [128 t][64 d] bf16,
  //            XOR-swizzled rows, double-buffered);
  //          [32768,51200) per-wave P tiles [4][4 st][16 s][36 t] u16;
  //          [51200,51456) Lbuf float[4][16].
  // Epilogue: Obuf float[4][16][66] (16896 B) aliases [0,16896) after sync.
  __shared__ __align__(16) char smem[51456];
  u16* const Ks0 = (u16*)smem;
  u16* const Ks1 = (u16*)(smem + 16384);
  const int tid = threadIdx.x, lane = tid & 63, w = tid >> 6;
  const int quad = lane >> 4, l16 = lane & 15;
  const int id = blockIdx.x;
  const int xcd = id & 7, idx = id >> 3;
  const int pair = xcd * 4 + (idx & 3);  // pair fast: 4 pairs pinned per XCD
  const int qt = idx >> 2;               // qt slow (0..31): 64 q-rows per block
  const int bb = pair >> 4, hh = pair & 15;
  const u16* Qp = Qw + pair * (2048 * 64);
  const u16* Kp = Kw + pair * (2048 * 64);
  const u16* Vp = Vw + pair * (64 * 2048);
  const int s0 = qt * 64;  // block's 64 q-rows (shared by all waves)
  char* const Pw = smem + 32768 + w * 4608;  // [4 st][16 s][36 t] u16 (pad 36)

  bf8a qf[4][2];  // B-operand (Q^T): [st][ks]; n=s, k=d  (Q pre-scaled by c1)
#pragma unroll
  for (int st = 0; st < 4; ++st)
#pragma unroll
    for (int ks = 0; ks < 2; ++ks)
      qf[st][ks] = *(const bf8a*)(Qp + (s0 + st * 16 + l16) * 64 + ks * 32 + quad * 8);

  f32x4 oacc[4][4];  // O^T partial: [st][nt]; e = nt*16+quad*4+r, s = st*16+l16
#pragma unroll
  for (int i = 0; i < 4; ++i)
#pragma unroll
    for (int j = 0; j < 4; ++j) oacc[i][j] = f32x4{0.f, 0.f, 0.f, 0.f};
  float lsum[4] = {0.f, 0.f, 0.f, 0.f};  // per-lane partial row-sum of |p|

  // DMA source pre-swizzle: lane writes LDS byte L=(c*4+w)*1024+lane*16
  // = row*128 + chunk*16 with row=(c*4+w)*8+(lane>>3), chunk=lane&7.
  // Stored-at-L content must be element at chunk^(row&7) = (lane&7)^(lane>>3).
  const int r8 = lane >> 3;
  const int c16s = (lane & 7) ^ r8;

  // prologue: stage 0 into Ks0, drain
  STAGE_K(Ks0, 0)
  __syncthreads();

  for (int kt = 0; kt < 16; kt += 2) {
    // phase A: prefetch kt+1 (DMA->Ks1), compute kt from Ks0
    STAGE_K(Ks1, kt + 1)
    COMPUTE(Ks0, kt)
    __syncthreads();  // kt+1 staged; all waves done reading Ks0
    // phase B: prefetch kt+2 (DMA->Ks0), compute kt+1 from Ks1
    if (kt < 14) {
      STAGE_K(Ks0, kt + 2)
    }
    COMPUTE(Ks1, kt + 1)
    __syncthreads();  // kt+2 staged; all waves done reading Ks1
  }

  // ---------------- merge epilogue (plain sums, 4 st-passes) ----------------
  float* const Obuf = (float*)smem;             // [4][16 s][66 e]
  float* const Lbuf = (float*)(smem + 51200);   // [4][16 s]
#pragma unroll
  for (int st = 0; st < 4; ++st) {
    float ls = lsum[st];
    ls += __shfl_xor(ls, 16);
    ls += __shfl_xor(ls, 32);
    if (lane < 16) Lbuf[w * 16 + l16] = ls;
#pragma unroll
    for (int nt = 0; nt < 4; ++nt)
      *(float4a*)&Obuf[w * 1056 + l16 * 66 + nt * 16 + quad * 4] = (float4){
          oacc[st][nt][0], oacc[st][nt][1], oacc[st][nt][2], oacc[st][nt][3]};
    __syncthreads();
    // sum across waves + write: s = tid&15, e = (tid>>4)*4 + [0,4)
    {
      const int s_ = tid & 15, eg = (tid >> 4) * 4;
      float a0 = 0.f, a1 = 0.f, a2 = 0.f, a3 = 0.f;
#pragma unroll
      for (int wp = 0; wp < 4; ++wp) {
        const float4 x = *(const float4a*)&Obuf[wp * 1056 + s_ * 66 + eg];
        a0 += x.x; a1 += x.y; a2 += x.z; a3 += x.w;
      }
      const float lt = Lbuf[s_] + Lbuf[16 + s_] + Lbuf[32 + s_] + Lbuf[48 + s_];
      const float inv = 1.0f / lt;
      ushort4 o;
      o.x = f2b(a0 * inv); o.y = f2b(a1 * inv); o.z = f2b(a2 * inv); o.w = f2b(a3 * inv);
      *(ushort4a*)(Ao + ((s0 + st * 16 + s_) * 2 + bb) * 1024 + hh * 64 + eg) = o;
    }
    if (st < 3) __syncthreads();  // before next pass overwrites Obuf/Lbuf
  }
}

// ---------------------------------------------------------------------------
extern "C" void kernel_launch(void* const* d_in, const int* in_sizes, int n_in,
                              void* d_out, int out_size, void* d_ws, size_t ws_size,
                              hipStream_t stream) {
  const float* src = (const float*)d_in[0];
  const float* eb = (const float*)d_in[1];
  const float* wq = (const float*)d_in[2];
  const float* bq = (const float*)d_in[3];
  const float* wk = (const float*)d_in[4];
  const float* bk = (const float*)d_in[5];
  const float* wv = (const float*)d_in[6];
  const float* bv = (const float*)d_in[7];
  const float* wo = (const float*)d_in[8];
  const float* bo = (const float*)d_in[9];
  u16* ws = (u16*)d_ws;
  const size_t MM = 1024 * 1024;
  u16* wqT = ws;             // bf16 [N][K]
  u16* wkT = ws + MM;
  u16* wvT = ws + 2 * MM;
  u16* woT = ws + 3 * MM;
  u16* srcB = ws + 4 * MM;   // bf16 [4096][1024] -- dead after QKV GEMM
  u16* eb2 = ws + 4 * MM;    // bf16 tiled signed-exp EB (aliases srcB, written after)
  u16* qW = ws + 8 * MM;     // bf16 [32][2048][64]  (pre-scaled by c1)
  u16* kW = ws + 12 * MM;    // bf16 [32][2048][64]
  u16* vW = ws + 16 * MM;    // bf16 [32][64][2048] (V^T)
  u16* aO = ws + 20 * MM;    // bf16 [4096][1024]
  float* out = (float*)d_out;
  const float c1 = 0.125f * 1.44269504088896340736f;  // scale * log2(e)

  prep_inputs<<<dim3(5120), 256, 0, stream>>>(src, srcB, wq, wk, wv, wo,
                                              wqT, wkT, wvT, woT);
  gemm_bt<<<dim3(8, 32, 3), 256, 0, stream>>>(srcB, wqT, wkT, wvT, bq, bk, bv,
                                              c1, 1.0f, 1.0f,
                                              qW, kW, vW, nullptr, 0);
  prep_eb<<<dim3(4096), 256, 0, stream>>>(eb, eb2);  // after QKV GEMM (aliases srcB)
  attn_fused<<<dim3(1024), 256, 0, stream>>>(qW, kW, vW, eb2, aO);
  gemm_bt<<<dim3(8, 32, 1), 256, 0, stream>>>(aO, woT, woT, woT, bo, bo, bo,
                                              1.0f, 1.0f, 1.0f,
                                              nullptr, nullptr, nullptr, out, 1);
}

// Round 8
// 276.205 us; speedup vs baseline: 1.2013x; 1.2013x over previous
//
#include <hip/hip_runtime.h>
#include <stdint.h>

typedef unsigned short u16;
typedef unsigned int u32;

typedef __bf16 bf8 __attribute__((ext_vector_type(8)));
typedef bf8 bf8a __attribute__((may_alias));
typedef float f32x4 __attribute__((ext_vector_type(4)));
typedef uint2 uint2a __attribute__((may_alias));
typedef ushort4 ushort4a __attribute__((may_alias));
typedef float4 float4a __attribute__((may_alias));

#define MFMA_BF16(a, b, c) __builtin_amdgcn_mfma_f32_16x16x32_bf16((a), (b), (c), 0, 0, 0)

__device__ __forceinline__ u16 f2b(float x) {
  u32 u = __float_as_uint(x);
  return (u16)((u + 0x7fffu + ((u >> 16) & 1u)) >> 16);  // RNE
}
__device__ __forceinline__ void async16(const u16* g, void* l) {
  __builtin_amdgcn_global_load_lds((const __attribute__((address_space(1))) u32*)g,
                                   (__attribute__((address_space(3))) u32*)l, 16, 0, 0);
}

// ---------------------------------------------------------------------------
// prep_inputs: fused {src fp32->bf16 convert (blocks 0..4095)} +
//              {4x weight transpose+convert (blocks 4096..5119)}
// ---------------------------------------------------------------------------
__global__ __launch_bounds__(256) void prep_inputs(
    const float* __restrict__ src, u16* __restrict__ dst,
    const float* __restrict__ w0, const float* __restrict__ w1,
    const float* __restrict__ w2, const float* __restrict__ w3,
    u16* __restrict__ t0, u16* __restrict__ t1, u16* __restrict__ t2, u16* __restrict__ t3) {
  const int bid = blockIdx.x, tid = threadIdx.x;
  if (bid < 4096) {  // convert_src
    const int i = bid * 256 + tid;
    float4 v = *(const float4a*)(src + i * 4);
    ushort4 o;
    o.x = f2b(v.x); o.y = f2b(v.y); o.z = f2b(v.z); o.w = f2b(v.w);
    *(ushort4a*)(dst + i * 4) = o;
    return;
  }
  const int b2 = bid - 4096;
  const int z = b2 >> 8, xy = b2 & 255;
  const int bx = xy & 15, by = xy >> 4;
  const float* W = z == 0 ? w0 : z == 1 ? w1 : z == 2 ? w2 : w3;
  u16* T = z == 0 ? t0 : z == 1 ? t1 : z == 2 ? t2 : t3;
  __shared__ __align__(8) u16 tile[64][68];
  const int ty = tid >> 4, tx = tid & 15;
  const int kb = by * 64, nb = bx * 64;
#pragma unroll
  for (int i = 0; i < 4; ++i) {
    int lk = ty + i * 16;
    float4 v = *(const float4a*)(W + (kb + lk) * 1024 + nb + tx * 4);
    ushort4 h;
    h.x = f2b(v.x); h.y = f2b(v.y); h.z = f2b(v.z); h.w = f2b(v.w);
    *(ushort4a*)&tile[lk][tx * 4] = h;
  }
  __syncthreads();
#pragma unroll
  for (int i = 0; i < 4; ++i) {
    int ln = ty + i * 16;
    ushort4 v;
    v.x = tile[tx * 4 + 0][ln];
    v.y = tile[tx * 4 + 1][ln];
    v.z = tile[tx * 4 + 2][ln];
    v.w = tile[tx * 4 + 3][ln];
    *(ushort4a*)(T + (nb + ln) * 1024 + kb + tx * 4) = v;
  }
}

// ---------------------------------------------------------------------------
// EB precompute: fp32 [2048][2048] -> bf16 sign(b)*exp(b), 16x16-tiled layout.
// ---------------------------------------------------------------------------
__global__ __launch_bounds__(256) void prep_eb(const float* __restrict__ EB,
                                               u16* __restrict__ E2) {
  const int gid = blockIdx.x * 256 + threadIdx.x;
  const int s = gid >> 9;            // 512 float4 per row
  const int t = (gid & 511) * 4;
  const float4 v = *(const float4a*)(EB + s * 2048 + t);
  const float c2 = 1.44269504088896340736f;  // log2(e)
  ushort4 o;
  o.x = f2b(__builtin_amdgcn_exp2f(v.x * c2)) | (u16)((__float_as_uint(v.x) >> 16) & 0x8000u);
  o.y = f2b(__builtin_amdgcn_exp2f(v.y * c2)) | (u16)((__float_as_uint(v.y) >> 16) & 0x8000u);
  o.z = f2b(__builtin_amdgcn_exp2f(v.z * c2)) | (u16)((__float_as_uint(v.z) >> 16) & 0x8000u);
  o.w = f2b(__builtin_amdgcn_exp2f(v.w * c2)) | (u16)((__float_as_uint(v.w) >> 16) & 0x8000u);
  const int ti = ((s >> 4) * 128 + (t >> 4)) * 256 + (s & 15) * 16 + (t & 15);
  *(ushort4a*)(E2 + ti) = o;
}

// ---------------------------------------------------------------------------
// GEMM: C[M][N] = (A[M,1024] * Bt[N,1024]^T + bias[n]) * scale  (m97 structure)
// z==2 (V^T) epilogue now repacks through LDS: the old direct store was u16
// at 4KB stride (per-lane different page -> no L2 merge -> ~32x write
// amplification). New path: stage each 128x64 col-half in LDS ([128][65]
// odd stride), then store 128B-contiguous segments of V^T.
// ---------------------------------------------------------------------------
__global__ __launch_bounds__(256) void gemm_bt(
    const u16* __restrict__ A,
    const u16* __restrict__ B0, const u16* __restrict__ B1, const u16* __restrict__ B2,
    const float* __restrict__ c0, const float* __restrict__ c1, const float* __restrict__ c2,
    float sc0, float sc1, float sc2,
    u16* __restrict__ O0, u16* __restrict__ O1, u16* __restrict__ O2,
    float* __restrict__ Of, int plain) {
  __shared__ __align__(16) u16 sm[8320];  // As/Bs (8192) in K-loop; [128][65] tile in V^T epilogue
  u16* As = sm;
  u16* Bs = sm + 4096;
  const int tid = threadIdx.x, lane = tid & 63, w = tid >> 6;
  const int wm = w >> 1, wn = w & 1, quad = lane >> 4, l16 = lane & 15;
  const int z = blockIdx.z;
  const u16* Bt = z == 0 ? B0 : (z == 1 ? B1 : B2);
  const float* bi = z == 0 ? c0 : (z == 1 ? c1 : c2);
  const float sc = z == 0 ? sc0 : (z == 1 ? sc1 : sc2);
  u16* O = z == 0 ? O0 : (z == 1 ? O1 : O2);
  const int row0 = blockIdx.y * 128, col0 = blockIdx.x * 128;

  f32x4 acc[4][4];
#pragma unroll
  for (int i = 0; i < 4; ++i)
#pragma unroll
    for (int j = 0; j < 4; ++j) acc[i][j] = f32x4{0.f, 0.f, 0.f, 0.f};

  const int e0 = tid, e1 = tid + 256;
  const int r0 = e0 >> 2, cc0 = (e0 & 3) * 8;
  const int r1 = e1 >> 2, cc1 = (e1 & 3) * 8;
  const u32 lb0 = (u32)(w * 64) * 16;
  const u32 lb1 = (u32)(w * 64 + 256) * 16;

  for (int k0 = 0; k0 < 1024; k0 += 32) {
    __syncthreads();
    async16(A + (row0 + r0) * 1024 + k0 + cc0, (char*)As + lb0);
    async16(A + (row0 + r1) * 1024 + k0 + cc1, (char*)As + lb1);
    async16(Bt + (col0 + r0) * 1024 + k0 + cc0, (char*)Bs + lb0);
    async16(Bt + (col0 + r1) * 1024 + k0 + cc1, (char*)Bs + lb1);
    __syncthreads();
    bf8a af[4], bfr[4];
#pragma unroll
    for (int i = 0; i < 4; ++i) {
      af[i] = *(const bf8a*)(As + (wm * 64 + i * 16 + l16) * 32 + quad * 8);
      bfr[i] = *(const bf8a*)(Bs + (wn * 64 + i * 16 + l16) * 32 + quad * 8);
    }
#pragma unroll
    for (int mt = 0; mt < 4; ++mt)
#pragma unroll
      for (int nt = 0; nt < 4; ++nt) acc[mt][nt] = MFMA_BF16(af[mt], bfr[nt], acc[mt][nt]);
  }

  if (!plain && z == 2) {
    // ---- V^T epilogue via LDS repack (2 column-halves of 64) ----
#pragma unroll
    for (int half = 0; half < 2; ++half) {
      __syncthreads();  // prev half's readers (or K-loop) done with sm
      if (wn == half) {
#pragma unroll
        for (int nt = 0; nt < 4; ++nt) {
          const int el = nt * 16 + l16;
          const float bcol = bi[col0 + half * 64 + el];
#pragma unroll
          for (int mt = 0; mt < 4; ++mt) {
#pragma unroll
            for (int r = 0; r < 4; ++r) {
              const int lr = wm * 64 + mt * 16 + quad * 4 + r;
              sm[lr * 65 + el] = f2b((acc[mt][nt][r] + bcol) * sc);
            }
          }
        }
      }
      __syncthreads();
      // read transposed, store 16B chunks: V^T[(p*64+e)*2048 + s]
      const int hh = (col0 >> 6) + half;
#pragma unroll
      for (int j = 0; j < 4; ++j) {
        const int idx = j * 256 + tid;
        const int sg = idx & 7, el = (idx >> 3) & 63, b_ = idx >> 9;
        ushort4 oa, ob;
        {
          const int base = (2 * (sg * 8) + b_) * 65 + el;
          oa.x = sm[base + 0 * 130]; oa.y = sm[base + 1 * 130];
          oa.z = sm[base + 2 * 130]; oa.w = sm[base + 3 * 130];
          ob.x = sm[base + 4 * 130]; ob.y = sm[base + 5 * 130];
          ob.z = sm[base + 6 * 130]; ob.w = sm[base + 7 * 130];
        }
        u16* dst = O + ((size_t)((b_ * 16 + hh) * 64 + el)) * 2048 + (row0 >> 1) + sg * 8;
        *(ushort4a*)dst = oa;
        *(ushort4a*)(dst + 4) = ob;
      }
    }
    return;
  }

#pragma unroll
  for (int nt = 0; nt < 4; ++nt) {
    const int col = col0 + wn * 64 + nt * 16 + l16;
    const float bcol = bi[col];
#pragma unroll
    for (int mt = 0; mt < 4; ++mt) {
#pragma unroll
      for (int r = 0; r < 4; ++r) {
        const int rm = row0 + wm * 64 + mt * 16 + quad * 4 + r;
        const float fv = (acc[mt][nt][r] + bcol) * sc;
        if (plain) {
          Of[rm * 1024 + col] = fv;
        } else {
          const u16 hv = f2b(fv);
          const int s = rm >> 1, b_ = rm & 1, hh = col >> 6, e = col & 63;
          const int p = b_ * 16 + hh;
          O[(p * 2048 + s) * 64 + e] = hv;  // [pair][s][64] (Q, K)
        }
      }
    }
  }
}

// ---------------------------------------------------------------------------
// Flash attention v16 = v13 chassis (QBLK=64, K via global_load_lds dbuf,
// XCD pinning, 2 waves/SIMD accepted) + PV/softmax cross-iteration pipeline:
//   per iter: pf(kt-1) ds_read -> STAGE_K(kt+1) -> S-MFMA(kt) -> PV(kt-1)
//   (independent MFMAs fill the pipe while sacc completes) -> softmax(kt)
//   VALU overlapped with PV tail -> P-write(kt) -> V(kt) into alternate reg
//   set (held across the barrier) -> barrier.
// P tile is PER-WAVE PRIVATE: pf(kt-1) is read before P(kt) overwrite in
// program order -> single P buffer, no extra barrier. EB JIT at iter top
// (covered by S+PV; saves 16 regs; peak ~228 under the (256,2) bound --
// r7 proved bound=3 spills this tile).
// ---------------------------------------------------------------------------
#define STAGE_K(Ksbuf, kt_)                                                         \
  {                                                                                 \
    _Pragma("unroll") for (int c = 0; c < 4; ++c) {                                 \
      const int row_ = c * 32 + w * 8 + r8;                                         \
      async16(Kp + ((kt_) * 128 + row_) * 64 + c16s * 8,                            \
              (char*)(Ksbuf) + (c * 4 + w) * 1024);                                 \
    }                                                                               \
  }

#define ITER(KsC, KsN, vfP, vfC, kt_, FIRST, LAST)                                  \
  {                                                                                 \
    bf8a pf[4];                                                                     \
    if (!(FIRST)) {                                                                 \
      _Pragma("unroll") for (int st = 0; st < 4; ++st)                              \
        pf[st] = *(const bf8a*)(Pw + st * 1152 + l16 * 72 + quad * 16);             \
    }                                                                               \
    if (!(LAST)) STAGE_K(KsN, (kt_) + 1)                                            \
    uint2 ebt[4][2]; /* JIT: L2-resident stripe, covered by S+PV below */           \
    {                                                                               \
      const int tb16_ = (kt_) * 8 + w * 2;                                          \
      _Pragma("unroll") for (int st = 0; st < 4; ++st)                              \
        _Pragma("unroll") for (int tt = 0; tt < 2; ++tt)                            \
          ebt[st][tt] = *(const uint2a*)(EBp + ((qt * 4 + st) * 128 + tb16_ + tt) * 256 \
                                         + l16 * 16 + quad * 4);                    \
    }                                                                               \
    bf8a kf[2][2];                                                                  \
    _Pragma("unroll") for (int tt = 0; tt < 2; ++tt) {                              \
      const int row_ = w * 32 + tt * 16 + l16; /* row_&7 == l16&7 */                \
      _Pragma("unroll") for (int ks = 0; ks < 2; ++ks) {                            \
        const int cc_ = ((ks * 4 + quad) ^ (l16 & 7)) * 8;                          \
        kf[tt][ks] = *(const bf8a*)((KsC) + row_ * 64 + cc_);                       \
      }                                                                             \
    }                                                                               \
    f32x4 sacc[4][2];                                                               \
    __builtin_amdgcn_s_setprio(1);                                                  \
    _Pragma("unroll") for (int tt = 0; tt < 2; ++tt)                                \
      _Pragma("unroll") for (int st = 0; st < 4; ++st) {                            \
        f32x4 t0_ = f32x4{0.f, 0.f, 0.f, 0.f};                                      \
        t0_ = MFMA_BF16(kf[tt][0], qf[st][0], t0_);                                 \
        sacc[st][tt] = MFMA_BF16(kf[tt][1], qf[st][1], t0_);                        \
      }                                                                             \
    if (!(FIRST)) { /* PV(kt-1): independent of sacc -> fills MFMA pipe */          \
      _Pragma("unroll") for (int st = 0; st < 4; ++st)                              \
        _Pragma("unroll") for (int nt = 0; nt < 4; ++nt)                            \
          oacc[st][nt] = MFMA_BF16(vfP[nt], pf[st], oacc[st][nt]);                  \
    }                                                                               \
    __builtin_amdgcn_s_setprio(0);                                                  \
    _Pragma("unroll") for (int st = 0; st < 4; ++st) {                              \
      _Pragma("unroll") for (int tt = 0; tt < 2; ++tt) {                            \
        const uint2 e_ = ebt[st][tt];                                               \
        const float g0 = __uint_as_float(e_.x << 16);                               \
        const float g1 = __uint_as_float(e_.x & 0xffff0000u);                       \
        const float g2 = __uint_as_float(e_.y << 16);                               \
        const float g3 = __uint_as_float(e_.y & 0xffff0000u);                       \
        const float p0 = __builtin_amdgcn_exp2f(sacc[st][tt][0]) * g0;              \
        const float p1 = __builtin_amdgcn_exp2f(sacc[st][tt][1]) * g1;              \
        const float p2 = __builtin_amdgcn_exp2f(sacc[st][tt][2]) * g2;              \
        const float p3 = __builtin_amdgcn_exp2f(sacc[st][tt][3]) * g3;              \
        lsum[st] += (__builtin_fabsf(p0) + __builtin_fabsf(p1)) +                   \
                    (__builtin_fabsf(p2) + __builtin_fabsf(p3));                    \
        const u16 h0 = __builtin_bit_cast(u16, (__bf16)p0);                         \
        const u16 h1 = __builtin_bit_cast(u16, (__bf16)p1);                         \
        const u16 h2 = __builtin_bit_cast(u16, (__bf16)p2);                         \
        const u16 h3 = __builtin_bit_cast(u16, (__bf16)p3);                         \
        uint2 v_;                                                                   \
        v_.x = (u32)h0 | ((u32)h1 << 16);                                           \
        v_.y = (u32)h2 | ((u32)h3 << 16);                                           \
        *(uint2a*)(Pw + st * 1152 + l16 * 72 + tt * 32 + quad * 8) = v_;            \
      }                                                                             \
    }                                                                               \
    { /* V(kt) -> alternate reg set, consumed by next iter's PV */                  \
      const int tb_ = (kt_) * 128 + w * 32;                                         \
      _Pragma("unroll") for (int nt = 0; nt < 4; ++nt)                              \
        vfC[nt] = *(const bf8a*)(Vp + (nt * 16 + l16) * 2048 + tb_ + quad * 8);     \
    }                                                                               \
    __syncthreads();                                                                \
  }

__global__ __launch_bounds__(256, 2) void attn_fused(
    const u16* __restrict__ Qw, const u16* __restrict__ Kw, const u16* __restrict__ Vw,
    const u16* __restrict__ EBp, u16* __restrict__ Ao) {
  // LDS map: [0,16384) Ks0, [16384,32768) Ks1 (K tile [128 t][64 d] bf16,
  //            XOR-swizzled rows, double-buffered);
  //          [32768,51200) per-wave P tiles [4][4 st][16 s][36 t] u16;
  //          [51200,51456) Lbuf float[4][16].
  // Epilogue: Obuf float[4][16][66] (16896 B) aliases Ks region after last barrier.
  __shared__ __align__(16) char smem[51456];
  u16* const Ks0 = (u16*)smem;
  u16* const Ks1 = (u16*)(smem + 16384);
  const int tid = threadIdx.x, lane = tid & 63, w = tid >> 6;
  const int quad = lane >> 4, l16 = lane & 15;
  const int id = blockIdx.x;
  const int xcd = id & 7, idx = id >> 3;
  const int pair = xcd * 4 + (idx & 3);  // pair fast: 4 pairs pinned per XCD
  const int qt = idx >> 2;               // qt slow (0..31): 64 q-rows per block
  const int bb = pair >> 4, hh = pair & 15;
  const u16* Qp = Qw + pair * (2048 * 64);
  const u16* Kp = Kw + pair * (2048 * 64);
  const u16* Vp = Vw + pair * (64 * 2048);
  const int s0 = qt * 64;  // block's 64 q-rows (shared by all waves)
  char* const Pw = smem + 32768 + w * 4608;  // [4 st][16 s][36 t] u16 (pad 36)

  bf8a qf[4][2];  // B-operand (Q^T): [st][ks]; n=s, k=d  (Q pre-scaled by c1)
#pragma unroll
  for (int st = 0; st < 4; ++st)
#pragma unroll
    for (int ks = 0; ks < 2; ++ks)
      qf[st][ks] = *(const bf8a*)(Qp + (s0 + st * 16 + l16) * 64 + ks * 32 + quad * 8);

  f32x4 oacc[4][4];  // O^T partial: [st][nt]; e = nt*16+quad*4+r, s = st*16+l16
#pragma unroll
  for (int i = 0; i < 4; ++i)
#pragma unroll
    for (int j = 0; j < 4; ++j) oacc[i][j] = f32x4{0.f, 0.f, 0.f, 0.f};
  float lsum[4] = {0.f, 0.f, 0.f, 0.f};  // per-lane partial row-sum of |p|

  // DMA source pre-swizzle (rule #21): lane writes LDS byte L=(c*4+w)*1024+lane*16
  // = row*128 + chunk*16; stored content = element at chunk^(row&7).
  const int r8 = lane >> 3;
  const int c16s = (lane & 7) ^ r8;

  bf8a vfA[4], vfB[4];

  // prologue: stage 0 into Ks0, drain
  STAGE_K(Ks0, 0)
  __syncthreads();

  // iter 0: no PV; produces vfA = V(0); stages Ks1(1)
  ITER(Ks0, Ks1, vfA /*unused*/, vfA, 0, 1, 0)
  // kt = 1..14 (7 x 2 phases)
  for (int kt = 1; kt < 14; kt += 2) {
    ITER(Ks1, Ks0, vfA, vfB, kt, 0, 0)
    ITER(Ks0, Ks1, vfB, vfA, kt + 1, 0, 0)
  }
  // kt = 15 (last: no stage); consumes vfA = V(14), produces vfB = V(15)
  ITER(Ks1, Ks0, vfA, vfB, 15, 0, 1)
  // final PV(15)
  {
    bf8a pf[4];
#pragma unroll
    for (int st = 0; st < 4; ++st)
      pf[st] = *(const bf8a*)(Pw + st * 1152 + l16 * 72 + quad * 16);
    __builtin_amdgcn_s_setprio(1);
#pragma unroll
    for (int st = 0; st < 4; ++st)
#pragma unroll
      for (int nt = 0; nt < 4; ++nt)
        oacc[st][nt] = MFMA_BF16(vfB[nt], pf[st], oacc[st][nt]);
    __builtin_amdgcn_s_setprio(0);
  }

  // ---------------- merge epilogue (plain sums, 4 st-passes) ----------------
  float* const Obuf = (float*)smem;             // [4][16 s][66 e] (aliases Ks)
  float* const Lbuf = (float*)(smem + 51200);   // [4][16 s]
#pragma unroll
  for (int st = 0; st < 4; ++st) {
    float ls = lsum[st];
    ls += __shfl_xor(ls, 16);
    ls += __shfl_xor(ls, 32);
    if (lane < 16) Lbuf[w * 16 + l16] = ls;
#pragma unroll
    for (int nt = 0; nt < 4; ++nt)
      *(float4a*)&Obuf[w * 1056 + l16 * 66 + nt * 16 + quad * 4] = (float4){
          oacc[st][nt][0], oacc[st][nt][1], oacc[st][nt][2], oacc[st][nt][3]};
    __syncthreads();
    // sum across waves + write: s = tid&15, e = (tid>>4)*4 + [0,4)
    {
      const int s_ = tid & 15, eg = (tid >> 4) * 4;
      float a0 = 0.f, a1 = 0.f, a2 = 0.f, a3 = 0.f;
#pragma unroll
      for (int wp = 0; wp < 4; ++wp) {
        const float4 x = *(const float4a*)&Obuf[wp * 1056 + s_ * 66 + eg];
        a0 += x.x; a1 += x.y; a2 += x.z; a3 += x.w;
      }
      const float lt = Lbuf[s_] + Lbuf[16 + s_] + Lbuf[32 + s_] + Lbuf[48 + s_];
      const float inv = 1.0f / lt;
      ushort4 o;
      o.x = f2b(a0 * inv); o.y = f2b(a1 * inv); o.z = f2b(a2 * inv); o.w = f2b(a3 * inv);
      *(ushort4a*)(Ao + ((s0 + st * 16 + s_) * 2 + bb) * 1024 + hh * 64 + eg) = o;
    }
    if (st < 3) __syncthreads();  // before next pass overwrites Obuf/Lbuf
  }
}

// ---------------------------------------------------------------------------
extern "C" void kernel_launch(void* const* d_in, const int* in_sizes, int n_in,
                              void* d_out, int out_size, void* d_ws, size_t ws_size,
                              hipStream_t stream) {
  const float* src = (const float*)d_in[0];
  const float* eb = (const float*)d_in[1];
  const float* wq = (const float*)d_in[2];
  const float* bq = (const float*)d_in[3];
  const float* wk = (const float*)d_in[4];
  const float* bk = (const float*)d_in[5];
  const float* wv = (const float*)d_in[6];
  const float* bv = (const float*)d_in[7];
  const float* wo = (const float*)d_in[8];
  const float* bo = (const float*)d_in[9];
  u16* ws = (u16*)d_ws;
  const size_t MM = 1024 * 1024;
  u16* wqT = ws;             // bf16 [N][K]
  u16* wkT = ws + MM;
  u16* wvT = ws + 2 * MM;
  u16* woT = ws + 3 * MM;
  u16* srcB = ws + 4 * MM;   // bf16 [4096][1024] -- dead after QKV GEMM
  u16* eb2 = ws + 4 * MM;    // bf16 tiled signed-exp EB (aliases srcB, written after)
  u16* qW = ws + 8 * MM;     // bf16 [32][2048][64]  (pre-scaled by c1)
  u16* kW = ws + 12 * MM;    // bf16 [32][2048][64]
  u16* vW = ws + 16 * MM;    // bf16 [32][64][2048] (V^T)
  u16* aO = ws + 20 * MM;    // bf16 [4096][1024]
  float* out = (float*)d_out;
  const float c1 = 0.125f * 1.44269504088896340736f;  // scale * log2(e)

  prep_inputs<<<dim3(5120), 256, 0, stream>>>(src, srcB, wq, wk, wv, wo,
                                              wqT, wkT, wvT, woT);
  gemm_bt<<<dim3(8, 32, 3), 256, 0, stream>>>(srcB, wqT, wkT, wvT, bq, bk, bv,
                                              c1, 1.0f, 1.0f,
                                              qW, kW, vW, nullptr, 0);
  prep_eb<<<dim3(4096), 256, 0, stream>>>(eb, eb2);  // after QKV GEMM (aliases srcB)
  attn_fused<<<dim3(1024), 256, 0, stream>>>(qW, kW, vW, eb2, aO);
  gemm_bt<<<dim3(8, 32, 1), 256, 0, stream>>>(aO, woT, woT, woT, bo, bo, bo,
                                              1.0f, 1.0f, 1.0f,
                                              nullptr, nullptr, nullptr, out, 1);
}

// Round 9
// 251.083 us; speedup vs baseline: 1.3215x; 1.1001x over previous
//
#include <hip/hip_runtime.h>
#include <stdint.h>

typedef unsigned short u16;
typedef unsigned int u32;

typedef __bf16 bf8 __attribute__((ext_vector_type(8)));
typedef bf8 bf8a __attribute__((may_alias));
typedef float f32x4 __attribute__((ext_vector_type(4)));
typedef uint2 uint2a __attribute__((may_alias));
typedef ushort4 ushort4a __attribute__((may_alias));
typedef float4 float4a __attribute__((may_alias));

#define MFMA_BF16(a, b, c) __builtin_amdgcn_mfma_f32_16x16x32_bf16((a), (b), (c), 0, 0, 0)

__device__ __forceinline__ u16 f2b(float x) {
  u32 u = __float_as_uint(x);
  return (u16)((u + 0x7fffu + ((u >> 16) & 1u)) >> 16);  // RNE
}
__device__ __forceinline__ void async16(const u16* g, void* l) {
  __builtin_amdgcn_global_load_lds((const __attribute__((address_space(1))) u32*)g,
                                   (__attribute__((address_space(3))) u32*)l, 16, 0, 0);
}

// ---------------------------------------------------------------------------
// prep_inputs: fused {src fp32->bf16 convert (blocks 0..4095)} +
//              {4x weight transpose+convert (blocks 4096..5119)}
// ---------------------------------------------------------------------------
__global__ __launch_bounds__(256) void prep_inputs(
    const float* __restrict__ src, u16* __restrict__ dst,
    const float* __restrict__ w0, const float* __restrict__ w1,
    const float* __restrict__ w2, const float* __restrict__ w3,
    u16* __restrict__ t0, u16* __restrict__ t1, u16* __restrict__ t2, u16* __restrict__ t3) {
  const int bid = blockIdx.x, tid = threadIdx.x;
  if (bid < 4096) {  // convert_src
    const int i = bid * 256 + tid;
    float4 v = *(const float4a*)(src + i * 4);
    ushort4 o;
    o.x = f2b(v.x); o.y = f2b(v.y); o.z = f2b(v.z); o.w = f2b(v.w);
    *(ushort4a*)(dst + i * 4) = o;
    return;
  }
  const int b2 = bid - 4096;
  const int z = b2 >> 8, xy = b2 & 255;
  const int bx = xy & 15, by = xy >> 4;
  const float* W = z == 0 ? w0 : z == 1 ? w1 : z == 2 ? w2 : w3;
  u16* T = z == 0 ? t0 : z == 1 ? t1 : z == 2 ? t2 : t3;
  __shared__ __align__(8) u16 tile[64][68];
  const int ty = tid >> 4, tx = tid & 15;
  const int kb = by * 64, nb = bx * 64;
#pragma unroll
  for (int i = 0; i < 4; ++i) {
    int lk = ty + i * 16;
    float4 v = *(const float4a*)(W + (kb + lk) * 1024 + nb + tx * 4);
    ushort4 h;
    h.x = f2b(v.x); h.y = f2b(v.y); h.z = f2b(v.z); h.w = f2b(v.w);
    *(ushort4a*)&tile[lk][tx * 4] = h;
  }
  __syncthreads();
#pragma unroll
  for (int i = 0; i < 4; ++i) {
    int ln = ty + i * 16;
    ushort4 v;
    v.x = tile[tx * 4 + 0][ln];
    v.y = tile[tx * 4 + 1][ln];
    v.z = tile[tx * 4 + 2][ln];
    v.w = tile[tx * 4 + 3][ln];
    *(ushort4a*)(T + (nb + ln) * 1024 + kb + tx * 4) = v;
  }
}

// ---------------------------------------------------------------------------
// EB precompute: fp32 [2048][2048] -> bf16 sign(b)*exp(b), 16x16-tiled layout.
// ---------------------------------------------------------------------------
__global__ __launch_bounds__(256) void prep_eb(const float* __restrict__ EB,
                                               u16* __restrict__ E2) {
  const int gid = blockIdx.x * 256 + threadIdx.x;
  const int s = gid >> 9;            // 512 float4 per row
  const int t = (gid & 511) * 4;
  const float4 v = *(const float4a*)(EB + s * 2048 + t);
  const float c2 = 1.44269504088896340736f;  // log2(e)
  ushort4 o;
  o.x = f2b(__builtin_amdgcn_exp2f(v.x * c2)) | (u16)((__float_as_uint(v.x) >> 16) & 0x8000u);
  o.y = f2b(__builtin_amdgcn_exp2f(v.y * c2)) | (u16)((__float_as_uint(v.y) >> 16) & 0x8000u);
  o.z = f2b(__builtin_amdgcn_exp2f(v.z * c2)) | (u16)((__float_as_uint(v.z) >> 16) & 0x8000u);
  o.w = f2b(__builtin_amdgcn_exp2f(v.w * c2)) | (u16)((__float_as_uint(v.w) >> 16) & 0x8000u);
  const int ti = ((s >> 4) * 128 + (t >> 4)) * 256 + (s & 15) * 16 + (t & 15);
  *(ushort4a*)(E2 + ti) = o;
}

// ---------------------------------------------------------------------------
// GEMM: C[M][N] = (A[M,1024] * Bt[N,1024]^T + bias[n]) * scale  (m97 structure)
// Epilogue reverted to direct stores (r8's V^T LDS-repack was a 12us
// regression: the per-block rm-rows land on the SAME 128B line per (p,e),
// so L2 write-coalescing already handles it).
// ---------------------------------------------------------------------------
__global__ __launch_bounds__(256) void gemm_bt(
    const u16* __restrict__ A,
    const u16* __restrict__ B0, const u16* __restrict__ B1, const u16* __restrict__ B2,
    const float* __restrict__ c0, const float* __restrict__ c1, const float* __restrict__ c2,
    float sc0, float sc1, float sc2,
    u16* __restrict__ O0, u16* __restrict__ O1, u16* __restrict__ O2,
    float* __restrict__ Of, int plain) {
  __shared__ __align__(16) u16 sm[8192];
  u16* As = sm;
  u16* Bs = sm + 4096;
  const int tid = threadIdx.x, lane = tid & 63, w = tid >> 6;
  const int wm = w >> 1, wn = w & 1, quad = lane >> 4, l16 = lane & 15;
  const int z = blockIdx.z;
  const u16* Bt = z == 0 ? B0 : (z == 1 ? B1 : B2);
  const float* bi = z == 0 ? c0 : (z == 1 ? c1 : c2);
  const float sc = z == 0 ? sc0 : (z == 1 ? sc1 : sc2);
  u16* O = z == 0 ? O0 : (z == 1 ? O1 : O2);
  const int row0 = blockIdx.y * 128, col0 = blockIdx.x * 128;

  f32x4 acc[4][4];
#pragma unroll
  for (int i = 0; i < 4; ++i)
#pragma unroll
    for (int j = 0; j < 4; ++j) acc[i][j] = f32x4{0.f, 0.f, 0.f, 0.f};

  const int e0 = tid, e1 = tid + 256;
  const int r0 = e0 >> 2, cc0 = (e0 & 3) * 8;
  const int r1 = e1 >> 2, cc1 = (e1 & 3) * 8;
  const u32 lb0 = (u32)(w * 64) * 16;
  const u32 lb1 = (u32)(w * 64 + 256) * 16;

  for (int k0 = 0; k0 < 1024; k0 += 32) {
    __syncthreads();
    async16(A + (row0 + r0) * 1024 + k0 + cc0, (char*)As + lb0);
    async16(A + (row0 + r1) * 1024 + k0 + cc1, (char*)As + lb1);
    async16(Bt + (col0 + r0) * 1024 + k0 + cc0, (char*)Bs + lb0);
    async16(Bt + (col0 + r1) * 1024 + k0 + cc1, (char*)Bs + lb1);
    __syncthreads();
    bf8a af[4], bfr[4];
#pragma unroll
    for (int i = 0; i < 4; ++i) {
      af[i] = *(const bf8a*)(As + (wm * 64 + i * 16 + l16) * 32 + quad * 8);
      bfr[i] = *(const bf8a*)(Bs + (wn * 64 + i * 16 + l16) * 32 + quad * 8);
    }
#pragma unroll
    for (int mt = 0; mt < 4; ++mt)
#pragma unroll
      for (int nt = 0; nt < 4; ++nt) acc[mt][nt] = MFMA_BF16(af[mt], bfr[nt], acc[mt][nt]);
  }

#pragma unroll
  for (int nt = 0; nt < 4; ++nt) {
    const int col = col0 + wn * 64 + nt * 16 + l16;
    const float bcol = bi[col];
#pragma unroll
    for (int mt = 0; mt < 4; ++mt) {
#pragma unroll
      for (int r = 0; r < 4; ++r) {
        const int rm = row0 + wm * 64 + mt * 16 + quad * 4 + r;
        const float fv = (acc[mt][nt][r] + bcol) * sc;
        if (plain) {
          Of[rm * 1024 + col] = fv;
        } else {
          const u16 hv = f2b(fv);
          const int s = rm >> 1, b_ = rm & 1, hh = col >> 6, e = col & 63;
          const int p = b_ * 16 + hh;
          if (z < 2) O[(p * 2048 + s) * 64 + e] = hv;  // [pair][s][64]
          else O[(p * 64 + e) * 2048 + s] = hv;        // [pair][e][s] (V^T)
        }
      }
    }
  }
}

// ---------------------------------------------------------------------------
// Flash attention v17: BARRIER-FREE main loop.
// Counter archaeology (v13/v15/v16 all ~98us): ~3600cy/iter of stall is
// invariant to intra-iteration restructuring. The invariant is the 2x
// per-iter __syncthreads, each a full vmcnt(0)+lgkmcnt(0) drain + 4-wave
// convoy with only 2 blocks/CU to cover it. But EVERY LDS structure here is
// per-wave private: wave w's kf reads come only from its own 32-row strip,
// P is per-wave. So the barriers synchronize nothing -> remove them all.
//  - per-wave K double-buffer (2 x 4KB), staged by the OWNING wave's
//    global_load_lds; DMA->ds_read ordering via asm s_waitcnt vmcnt(4)
//    (+sched_barrier, rule #18): allows the 4 in-flight V loads to stay
//    outstanding, drains everything older (in-order retirement => exact).
//  - waves free-run and desync (setprio now has waves at different phases
//    to arbitrate -- T5's mechanism).
//  - running pointers for K/EB/V (saves ~60 addr-VALU/iter).
//  - PV cross-iteration pipeline and all v16 numerics kept (bit-identical).
// Epilogue: one __syncthreads resyncs before Obuf aliases the K region.
// ---------------------------------------------------------------------------
#define STAGE_K(Ksbuf)                                                              \
  {                                                                                 \
    _Pragma("unroll") for (int c = 0; c < 4; ++c)                                   \
      async16(kpt + c * 512, (char*)(Ksbuf) + c * 1024);                            \
    kpt += 8192;                                                                    \
  }

#define ITER(KsC, KsN, vfP, vfC, FIRST, LAST)                                       \
  {                                                                                 \
    /* DMA(this tile) drain; keep V(prev) in flight. memory clobber pins */         \
    /* the following ds_reads behind the wait (rule #18). */                        \
    asm volatile("s_waitcnt vmcnt(4)" ::: "memory");                                \
    __builtin_amdgcn_sched_barrier(0);                                              \
    bf8a pf[4];                                                                     \
    if (!(FIRST)) {                                                                 \
      _Pragma("unroll") for (int st = 0; st < 4; ++st)                              \
        pf[st] = *(const bf8a*)(Pw + st * 1152 + l16 * 72 + quad * 16);             \
    }                                                                               \
    bf8a kf[2][2];                                                                  \
    _Pragma("unroll") for (int tt = 0; tt < 2; ++tt) {                              \
      const int rl_ = tt * 16 + l16; /* local row; rl_&7 == l16&7 */                \
      _Pragma("unroll") for (int ks = 0; ks < 2; ++ks) {                            \
        const int cc_ = ((ks * 4 + quad) ^ (l16 & 7)) * 8;                          \
        kf[tt][ks] = *(const bf8a*)((KsC) + rl_ * 64 + cc_);                        \
      }                                                                             \
    }                                                                               \
    if (!(LAST)) STAGE_K(KsN)                                                       \
    uint2 ebt[4][2];                                                                \
    _Pragma("unroll") for (int st = 0; st < 4; ++st)                                \
      _Pragma("unroll") for (int tt = 0; tt < 2; ++tt)                              \
        ebt[st][tt] = *(const uint2a*)(ebpt + st * 32768 + tt * 256);               \
    ebpt += 2048;                                                                   \
    f32x4 sacc[4][2];                                                               \
    __builtin_amdgcn_s_setprio(1);                                                  \
    _Pragma("unroll") for (int tt = 0; tt < 2; ++tt)                                \
      _Pragma("unroll") for (int st = 0; st < 4; ++st) {                            \
        f32x4 t0_ = f32x4{0.f, 0.f, 0.f, 0.f};                                      \
        t0_ = MFMA_BF16(kf[tt][0], qf[st][0], t0_);                                 \
        sacc[st][tt] = MFMA_BF16(kf[tt][1], qf[st][1], t0_);                        \
      }                                                                             \
    if (!(FIRST)) { /* PV(prev): independent of sacc -> fills MFMA pipe */          \
      _Pragma("unroll") for (int st = 0; st < 4; ++st)                              \
        _Pragma("unroll") for (int nt = 0; nt < 4; ++nt)                            \
          oacc[st][nt] = MFMA_BF16(vfP[nt], pf[st], oacc[st][nt]);                  \
    }                                                                               \
    __builtin_amdgcn_s_setprio(0);                                                  \
    _Pragma("unroll") for (int st = 0; st < 4; ++st) {                              \
      _Pragma("unroll") for (int tt = 0; tt < 2; ++tt) {                            \
        const uint2 e_ = ebt[st][tt];                                               \
        const float g0 = __uint_as_float(e_.x << 16);                               \
        const float g1 = __uint_as_float(e_.x & 0xffff0000u);                       \
        const float g2 = __uint_as_float(e_.y << 16);                               \
        const float g3 = __uint_as_float(e_.y & 0xffff0000u);                       \
        const float p0 = __builtin_amdgcn_exp2f(sacc[st][tt][0]) * g0;              \
        const float p1 = __builtin_amdgcn_exp2f(sacc[st][tt][1]) * g1;              \
        const float p2 = __builtin_amdgcn_exp2f(sacc[st][tt][2]) * g2;              \
        const float p3 = __builtin_amdgcn_exp2f(sacc[st][tt][3]) * g3;              \
        lsum[st] += (__builtin_fabsf(p0) + __builtin_fabsf(p1)) +                   \
                    (__builtin_fabsf(p2) + __builtin_fabsf(p3));                    \
        const u16 h0 = __builtin_bit_cast(u16, (__bf16)p0);                         \
        const u16 h1 = __builtin_bit_cast(u16, (__bf16)p1);                         \
        const u16 h2 = __builtin_bit_cast(u16, (__bf16)p2);                         \
        const u16 h3 = __builtin_bit_cast(u16, (__bf16)p3);                         \
        uint2 v_;                                                                   \
        v_.x = (u32)h0 | ((u32)h1 << 16);                                           \
        v_.y = (u32)h2 | ((u32)h3 << 16);                                           \
        *(uint2a*)(Pw + st * 1152 + l16 * 72 + tt * 32 + quad * 8) = v_;            \
      }                                                                             \
    }                                                                               \
    { /* V(this tile) -> alternate reg set, consumed by next iter's PV */           \
      _Pragma("unroll") for (int nt = 0; nt < 4; ++nt)                              \
        vfC[nt] = *(const bf8a*)(vpt + nt * 32768);                                 \
      vpt += 128;                                                                   \
    }                                                                               \
  }

__global__ __launch_bounds__(256, 2) void attn_fused(
    const u16* __restrict__ Qw, const u16* __restrict__ Kw, const u16* __restrict__ Vw,
    const u16* __restrict__ EBp, u16* __restrict__ Ao) {
  // LDS map: [0,32768) per-wave K dbuf: wave w owns [w*8192, w*8192+8192)
  //            = Ks0 (4KB) + Ks1 (4KB), 32 rows x 64 d bf16, XOR-swizzled;
  //          [32768,51200) per-wave P tiles [4][4 st][16 s][36 t] u16;
  //          [51200,51456) Lbuf float[4][16].
  // Epilogue: Obuf float[4][16][66] (16896 B) aliases the K region after
  // the resync barrier.
  __shared__ __align__(16) char smem[51456];
  const int tid = threadIdx.x, lane = tid & 63, w = tid >> 6;
  const int quad = lane >> 4, l16 = lane & 15;
  const int id = blockIdx.x;
  const int xcd = id & 7, idx = id >> 3;
  const int pair = xcd * 4 + (idx & 3);  // pair fast: 4 pairs pinned per XCD
  const int qt = idx >> 2;               // qt slow (0..31): 64 q-rows per block
  const int bb = pair >> 4, hh = pair & 15;
  const u16* Qp = Qw + pair * (2048 * 64);
  const u16* Kp = Kw + pair * (2048 * 64);
  const u16* Vp = Vw + pair * (64 * 2048);
  const int s0 = qt * 64;  // block's 64 q-rows (shared by all waves)
  u16* const Ks0 = (u16*)(smem + w * 8192);
  u16* const Ks1 = (u16*)(smem + w * 8192 + 4096);
  char* const Pw = smem + 32768 + w * 4608;  // [4 st][16 s][36 t] u16 (pad 36)

  bf8a qf[4][2];  // B-operand (Q^T): [st][ks]; n=s, k=d  (Q pre-scaled by c1)
#pragma unroll
  for (int st = 0; st < 4; ++st)
#pragma unroll
    for (int ks = 0; ks < 2; ++ks)
      qf[st][ks] = *(const bf8a*)(Qp + (s0 + st * 16 + l16) * 64 + ks * 32 + quad * 8);

  f32x4 oacc[4][4];  // O^T partial: [st][nt]; e = nt*16+quad*4+r, s = st*16+l16
#pragma unroll
  for (int i = 0; i < 4; ++i)
#pragma unroll
    for (int j = 0; j < 4; ++j) oacc[i][j] = f32x4{0.f, 0.f, 0.f, 0.f};
  float lsum[4] = {0.f, 0.f, 0.f, 0.f};  // per-lane partial row-sum of |p|

  // Per-wave K DMA: lane l of issue c writes LDS byte c*1024 + l*16 =
  // localrow*128 + chunk*16 with localrow = c*8 + (l>>3), chunk = l&7.
  // Swizzled source content: element chunk^(localrow&7) = (l&7)^(l>>3).
  const int r8 = lane >> 3;
  const int c16s = (lane & 7) ^ r8;
  // running pointers (addr-VALU diet)
  const u16* kpt = Kp + (w * 32 + r8) * 64 + c16s * 8;                  // += 8192/iter
  const u16* ebpt = EBp + (qt * 4 * 128 + w * 2) * 256 + l16 * 16 + quad * 4;  // += 2048/iter
  const u16* vpt = Vp + l16 * 2048 + w * 32 + quad * 8;                 // += 128/iter

  bf8a vfA[4], vfB[4];

  // prologue: stage tile 0 into own Ks0; full drain (first ITER's vmcnt(4)
  // would not wait with only 4 outstanding)
  STAGE_K(Ks0)
  asm volatile("s_waitcnt vmcnt(0)" ::: "memory");
  __builtin_amdgcn_sched_barrier(0);

  // iter 0: no PV; produces vfA = V(0); stages Ks1(1)
  ITER(Ks0, Ks1, vfA /*unused*/, vfA, 1, 0)
  // kt = 1..14 (7 x 2 phases)
  for (int it = 0; it < 7; ++it) {
    ITER(Ks1, Ks0, vfA, vfB, 0, 0)
    ITER(Ks0, Ks1, vfB, vfA, 0, 0)
  }
  // kt = 15 (last: no stage); consumes vfA = V(14), produces vfB = V(15)
  ITER(Ks1, Ks0, vfA, vfB, 0, 1)
  // final PV(15)
  {
    bf8a pf[4];
#pragma unroll
    for (int st = 0; st < 4; ++st)
      pf[st] = *(const bf8a*)(Pw + st * 1152 + l16 * 72 + quad * 16);
    __builtin_amdgcn_s_setprio(1);
#pragma unroll
    for (int st = 0; st < 4; ++st)
#pragma unroll
      for (int nt = 0; nt < 4; ++nt)
        oacc[st][nt] = MFMA_BF16(vfB[nt], pf[st], oacc[st][nt]);
    __builtin_amdgcn_s_setprio(0);
  }

  // ---------------- merge epilogue (plain sums, 4 st-passes) ----------------
  __syncthreads();  // resync: all waves done with their Ks/P before aliasing
  float* const Obuf = (float*)smem;             // [4][16 s][66 e] (aliases Ks)
  float* const Lbuf = (float*)(smem + 51200);   // [4][16 s]
#pragma unroll
  for (int st = 0; st < 4; ++st) {
    float ls = lsum[st];
    ls += __shfl_xor(ls, 16);
    ls += __shfl_xor(ls, 32);
    if (lane < 16) Lbuf[w * 16 + l16] = ls;
#pragma unroll
    for (int nt = 0; nt < 4; ++nt)
      *(float4a*)&Obuf[w * 1056 + l16 * 66 + nt * 16 + quad * 4] = (float4){
          oacc[st][nt][0], oacc[st][nt][1], oacc[st][nt][2], oacc[st][nt][3]};
    __syncthreads();
    // sum across waves + write: s = tid&15, e = (tid>>4)*4 + [0,4)
    {
      const int s_ = tid & 15, eg = (tid >> 4) * 4;
      float a0 = 0.f, a1 = 0.f, a2 = 0.f, a3 = 0.f;
#pragma unroll
      for (int wp = 0; wp < 4; ++wp) {
        const float4 x = *(const float4a*)&Obuf[wp * 1056 + s_ * 66 + eg];
        a0 += x.x; a1 += x.y; a2 += x.z; a3 += x.w;
      }
      const float lt = Lbuf[s_] + Lbuf[16 + s_] + Lbuf[32 + s_] + Lbuf[48 + s_];
      const float inv = 1.0f / lt;
      ushort4 o;
      o.x = f2b(a0 * inv); o.y = f2b(a1 * inv); o.z = f2b(a2 * inv); o.w = f2b(a3 * inv);
      *(ushort4a*)(Ao + ((s0 + st * 16 + s_) * 2 + bb) * 1024 + hh * 64 + eg) = o;
    }
    if (st < 3) __syncthreads();  // before next pass overwrites Obuf/Lbuf
  }
}

// ---------------------------------------------------------------------------
extern "C" void kernel_launch(void* const* d_in, const int* in_sizes, int n_in,
                              void* d_out, int out_size, void* d_ws, size_t ws_size,
                              hipStream_t stream) {
  const float* src = (const float*)d_in[0];
  const float* eb = (const float*)d_in[1];
  const float* wq = (const float*)d_in[2];
  const float* bq = (const float*)d_in[3];
  const float* wk = (const float*)d_in[4];
  const float* bk = (const float*)d_in[5];
  const float* wv = (const float*)d_in[6];
  const float* bv = (const float*)d_in[7];
  const float* wo = (const float*)d_in[8];
  const float* bo = (const float*)d_in[9];
  u16* ws = (u16*)d_ws;
  const size_t MM = 1024 * 1024;
  u16* wqT = ws;             // bf16 [N][K]
  u16* wkT = ws + MM;
  u16* wvT = ws + 2 * MM;
  u16* woT = ws + 3 * MM;
  u16* srcB = ws + 4 * MM;   // bf16 [4096][1024] -- dead after QKV GEMM
  u16* eb2 = ws + 4 * MM;    // bf16 tiled signed-exp EB (aliases srcB, written after)
  u16* qW = ws + 8 * MM;     // bf16 [32][2048][64]  (pre-scaled by c1)
  u16* kW = ws + 12 * MM;    // bf16 [32][2048][64]
  u16* vW = ws + 16 * MM;    // bf16 [32][64][2048] (V^T)
  u16* aO = ws + 20 * MM;    // bf16 [4096][1024]
  float* out = (float*)d_out;
  const float c1 = 0.125f * 1.44269504088896340736f;  // scale * log2(e)

  prep_inputs<<<dim3(5120), 256, 0, stream>>>(src, srcB, wq, wk, wv, wo,
                                              wqT, wkT, wvT, woT);
  gemm_bt<<<dim3(8, 32, 3), 256, 0, stream>>>(srcB, wqT, wkT, wvT, bq, bk, bv,
                                              c1, 1.0f, 1.0f,
                                              qW, kW, vW, nullptr, 0);
  prep_eb<<<dim3(4096), 256, 0, stream>>>(eb, eb2);  // after QKV GEMM (aliases srcB)
  attn_fused<<<dim3(1024), 256, 0, stream>>>(qW, kW, vW, eb2, aO);
  gemm_bt<<<dim3(8, 32, 1), 256, 0, stream>>>(aO, woT, woT, woT, bo, bo, bo,
                                              1.0f, 1.0f, 1.0f,
                                              nullptr, nullptr, nullptr, out, 1);
}